// Round 1
// baseline (214.403 us; speedup 1.0000x reference)
//
#include <hip/hip_runtime.h>

#define NB 16
#define CC 4
#define HH 32
#define WW 32
#define SS 1024

typedef float f4 __attribute__((ext_vector_type(4)));

// Main kernel with FUSED unfold: x (256 KB, L2-resident) is unfolded directly
// into the XT LDS tile during staging, eliminating the separate unfold kernel,
// the 2.36 MB xu HBM write, and main's 18.9 MB of xu re-reads.
//
// block = (s-tile of 16, v-PAIR); 576 threads = 16 sl x 36 float4-quads over the
// 144-float [c][o][k] row. XT is v-independent: one staging serves both v slabs.
// grid = 512 = exactly 2 blocks/CU. Each thread accumulates over u only (one
// (c,o,k) per vector element, per v); c-reduction in LDS.
__global__ __launch_bounds__(576) void main_kernel(
    const float* __restrict__ x,
    const float* __restrict__ wgt,
    const float* __restrict__ chan_map,
    const float* __restrict__ mask,
    float* __restrict__ mapped)
{
    __shared__ __align__(16) float XT[16 * 16 * 36];   // [u][sl][k*4+c]  36.9 KB
    __shared__ __align__(16) float CM[2 * 16 * 16];    // [vi][u][o*4+c]   2 KB
    __shared__ __align__(16) float4 RED[2 * 16 * 36];  // [vi][sl][q]     18.4 KB
    const int v0  = blockIdx.y * 2;
    const int s0  = blockIdx.x * 16;
    const int tid = threadIdx.x;

    // Fused unfold stage: XT[u][sl][k*4+c] = x[u,c,h,w] (zero-padded).
    // Each thread owns one (sl,k,c) slot for all 16 u. s-tile of 16 never
    // crosses an h-row (s0 % 16 == 0, 16|32), so h depends only on (s0,k).
    {
        const int sl = tid / 36;
        const int j  = tid % 36;        // j = k*4 + c
        const int k  = j >> 2;          // 0..8
        const int c  = j & 3;
        const int h  = (s0 >> 5) + (k / 3) - 1;
        const int w  = (s0 & 31) + sl + (k % 3) - 1;
        const bool ok = (h >= 0) && (h < HH) && (w >= 0) && (w < WW);
        const float* xp = x + (c * HH + h) * WW + w;   // + u*CC*HH*WW per u
#pragma unroll
        for (int u = 0; u < 16; ++u) {
            // LDS write addr word = tid + u*576: consecutive lanes -> consecutive
            // banks, conflict-free. x loads are scalar but L1/L2-hit (x = 256 KB).
            XT[u * 576 + tid] = ok ? xp[u * (CC * HH * WW)] : 0.f;
        }
    }
    // combined chan_map*mask for both v, transposed to [vi][u][o][c]
    if (tid < 512) {
        int vi = tid >> 8, rem = tid & 255;
        int u = rem >> 4, o = (rem >> 2) & 3, c = rem & 3;
        int v = v0 + vi;
        CM[tid] = chan_map[((u * 16 + v) * 4 + c) * 4 + o] * mask[u * 16 + v];
    }
    __syncthreads();

    const int sl = tid / 36;
    const int q  = tid % 36;          // float4 index into the 144-float row
    const int s  = s0 + sl;

    // decompose the 4 row elements r=4q+e into (c,o,k); r = c*36 + o*9 + k
    int xt_off[4], cm_off[4];
#pragma unroll
    for (int e = 0; e < 4; ++e) {
        int r = 4 * q + e;
        int c = r / 36;
        int o = (r / 9) & 3;
        int k = r % 9;
        xt_off[e] = sl * 36 + k * 4 + c;
        cm_off[e] = o * 4 + c;
    }

    const float* wp0 = wgt + (size_t)v0 * 147456 + (size_t)s * 144 + 4 * q;
    const float* wp1 = wp0 + 147456;
    f4 acc0 = (f4)0.f, acc1 = (f4)0.f;
#pragma unroll 4
    for (int u = 0; u < 16; ++u) {
        f4 wa = __builtin_nontemporal_load((const f4*)(wp0 + (size_t)u * 2359296));
        f4 wb = __builtin_nontemporal_load((const f4*)(wp1 + (size_t)u * 2359296));
        float x0 = XT[u * 576 + xt_off[0]], x1 = XT[u * 576 + xt_off[1]];
        float x2 = XT[u * 576 + xt_off[2]], x3 = XT[u * 576 + xt_off[3]];
        float ca0 = CM[u * 16 + cm_off[0]],       ca1 = CM[u * 16 + cm_off[1]];
        float ca2 = CM[u * 16 + cm_off[2]],       ca3 = CM[u * 16 + cm_off[3]];
        float cb0 = CM[256 + u * 16 + cm_off[0]], cb1 = CM[256 + u * 16 + cm_off[1]];
        float cb2 = CM[256 + u * 16 + cm_off[2]], cb3 = CM[256 + u * 16 + cm_off[3]];
        acc0.x += wa.x * x0 * ca0;  acc1.x += wb.x * x0 * cb0;
        acc0.y += wa.y * x1 * ca1;  acc1.y += wb.y * x1 * cb1;
        acc0.z += wa.z * x2 * ca2;  acc1.z += wb.z * x2 * cb2;
        acc0.w += wa.w * x3 * ca3;  acc1.w += wb.w * x3 * cb3;
    }

    // cross-thread c-reduction: threads {q, q+9, q+18, q+27} hold c=0..3 partials
    // for the same four (o,k) pairs (element-wise), per v.
    RED[sl * 36 + q]       = make_float4(acc0.x, acc0.y, acc0.z, acc0.w);
    RED[576 + sl * 36 + q] = make_float4(acc1.x, acc1.y, acc1.z, acc1.w);
    __syncthreads();
    if (q < 9) {
#pragma unroll
        for (int vi = 0; vi < 2; ++vi) {
            float4 t0 = RED[vi * 576 + sl * 36 + q];
            float4 t1 = RED[vi * 576 + sl * 36 + q + 9];
            float4 t2 = RED[vi * 576 + sl * 36 + q + 18];
            float4 t3 = RED[vi * 576 + sl * 36 + q + 27];
            float tot[4] = { t0.x + t1.x + t2.x + t3.x,
                             t0.y + t1.y + t2.y + t3.y,
                             t0.z + t1.z + t2.z + t3.z,
                             t0.w + t1.w + t2.w + t3.w };
            float* mp = mapped + (v0 + vi) * (SS * 36) + s * 36;
#pragma unroll
            for (int e = 0; e < 4; ++e) {
                int r = 4 * q + e;        // r = o*9 + k  (c=0 block)
                int o = r / 9, k = r % 9;
                mp[k * 4 + o] = tot[e];
            }
        }
    }
}

// Kernel C: fold with torch's channel reinterpretation: flat channel (k*4+o) read back as (c*9+i*3+j)
__global__ void fold_kernel(const float* __restrict__ mapped, float* __restrict__ out) {
    int t = blockIdx.x * blockDim.x + threadIdx.x;
    if (t >= NB * CC * HH * WW) return;
    int xx = t & 31, y = (t >> 5) & 31, c = (t >> 10) & 3, v = t >> 12;
    float sum = 0.f;
#pragma unroll
    for (int i = 0; i < 3; ++i) {
        int h = y + 1 - i;
        if (h < 0 || h >= HH) continue;
#pragma unroll
        for (int j = 0; j < 3; ++j) {
            int w = xx + 1 - j;
            if (w < 0 || w >= WW) continue;
            sum += mapped[v * (SS * 36) + (h * 32 + w) * 36 + (c * 9 + i * 3 + j)];
        }
    }
    out[t] = sum;
}

extern "C" void kernel_launch(void* const* d_in, const int* in_sizes, int n_in,
                              void* d_out, int out_size, void* d_ws, size_t ws_size,
                              hipStream_t stream) {
    const float* x    = (const float*)d_in[0];
    const float* wgt  = (const float*)d_in[1];
    const float* cmap = (const float*)d_in[2];
    const float* mask = (const float*)d_in[3];
    float* out = (float*)d_out;

    float* mapped = (float*)d_ws;                 // 589,824 floats = 2.36 MB

    main_kernel<<<dim3(SS / 16, NB / 2), 576, 0, stream>>>(x, wgt, cmap, mask, mapped);
    fold_kernel<<<(NB * CC * HH * WW + 255) / 256, 256, 0, stream>>>(mapped, out);
}

// Round 3
// 213.385 us; speedup vs baseline: 1.0048x; 1.0048x over previous
//
#include <hip/hip_runtime.h>

#define NB 16
#define CC 4
#define HH 32
#define WW 32
#define SS 1024

typedef float f4 __attribute__((ext_vector_type(4)));

// Fused unfold + main contraction.
//
// Staging is two-phase to keep global loads fully coalesced:
//   Phase 1: raw x rows for this block's 3-row halo -> XR[u][c][hh][w] in LDS,
//            1536 contiguous float4 loads (zero-filled for h out of range).
//   Phase 2: LDS->LDS rearrange into XT[u][sl][k*4+c] (w-predicated), so the
//            hot loop's fragment layout is unchanged from the verified kernel.
// XR (24.6 KB, staging-only) and RED (18.4 KB, epilogue-only) share one LDS
// pool: lifetimes are disjoint (last XR read precedes the pre-main barrier;
// first RED write follows the main loop). Total static LDS 62 KB < 64 KB.
//
// block = (s-tile of 16, v-PAIR); 576 threads = 16 sl x 36 float4-quads over
// the 144-float [c][o][k] row. XT is v-independent: one staging serves both v
// slabs. grid = 512 = exactly 2 blocks/CU. Each thread accumulates over u only;
// c-reduction in LDS.
__global__ __launch_bounds__(576) void main_kernel(
    const float* __restrict__ x,
    const float* __restrict__ wgt,
    const float* __restrict__ chan_map,
    const float* __restrict__ mask,
    float* __restrict__ mapped)
{
    __shared__ __align__(16) float XT[16 * 16 * 36];        // [u][sl][k*4+c] 36.9 KB
    __shared__ __align__(16) float CM[2 * 16 * 16];         // [vi][u][o*4+c]  2 KB
    __shared__ __align__(16) float POOL[16 * 4 * 3 * 32];   // XR / RED union 24.6 KB
    const int v0  = blockIdx.y * 2;
    const int s0  = blockIdx.x * 16;
    const int tid = threadIdx.x;
    const int h0  = s0 >> 5;          // row of this s-tile (tile never crosses rows)
    const int w0  = s0 & 31;          // 0 or 16

    // Phase 1: coalesced staging of raw x rows h0-1..h0+1 (all 32 w) for all u,c.
    // 1536 float4 = 24 KB; consecutive threads -> consecutive float4 addresses.
    {
        const f4* x4  = (const f4*)x;
        f4*       xr4 = (f4*)POOL;
#pragma unroll
        for (int i = 0; i < 3; ++i) {
            int t = tid + i * 576;
            if (t < 1536) {
                int u = t / 96, rem = t % 96;        // 96 float4 per u (4c*3hh*8wq)
                int c = rem / 24, rem2 = rem % 24;
                int hh = rem2 / 8, wq = rem2 % 8;
                int h = h0 + hh - 1;
                f4 v = (f4)0.f;
                if (h >= 0 && h < HH)
                    v = x4[((u * 4 + c) * 32 + h) * 8 + wq];
                xr4[t] = v;                          // conflict-free: lane -> bank
            }
        }
    }
    // combined chan_map*mask for both v, transposed to [vi][u][o][c]
    if (tid < 512) {
        int vi = tid >> 8, rem = tid & 255;
        int u = rem >> 4, o = (rem >> 2) & 3, c = rem & 3;
        int v = v0 + vi;
        CM[tid] = chan_map[((u * 16 + v) * 4 + c) * 4 + o] * mask[u * 16 + v];
    }
    __syncthreads();

    // Phase 2: build XT[u][sl][k*4+c] from XR (LDS->LDS). h-padding is already
    // baked into XR zeros; only w needs predication (fixed per thread).
    {
        const int slb = tid / 36;
        const int jb  = tid % 36;       // j = k*4 + c
        const int kb  = jb >> 2;        // 0..8
        const int cb  = jb & 3;
        const int hh  = kb / 3;
        const int w   = w0 + slb + (kb % 3) - 1;
        const bool ok = (unsigned)w < (unsigned)WW;
        const int base = (cb * 3 + hh) * 32 + (ok ? w : 0);
#pragma unroll
        for (int u = 0; u < 16; ++u)
            XT[u * 576 + tid] = ok ? POOL[u * 384 + base] : 0.f;
    }
    __syncthreads();

    const int sl = tid / 36;
    const int q  = tid % 36;          // float4 index into the 144-float row
    const int s  = s0 + sl;

    // decompose the 4 row elements r=4q+e into (c,o,k); r = c*36 + o*9 + k
    int xt_off[4], cm_off[4];
#pragma unroll
    for (int e = 0; e < 4; ++e) {
        int r = 4 * q + e;
        int c = r / 36;
        int o = (r / 9) & 3;
        int k = r % 9;
        xt_off[e] = sl * 36 + k * 4 + c;
        cm_off[e] = o * 4 + c;
    }

    const float* wp0 = wgt + (size_t)v0 * 147456 + (size_t)s * 144 + 4 * q;
    const float* wp1 = wp0 + 147456;
    f4 acc0 = (f4)0.f, acc1 = (f4)0.f;
#pragma unroll 4
    for (int u = 0; u < 16; ++u) {
        f4 wa = __builtin_nontemporal_load((const f4*)(wp0 + (size_t)u * 2359296));
        f4 wb = __builtin_nontemporal_load((const f4*)(wp1 + (size_t)u * 2359296));
        float x0 = XT[u * 576 + xt_off[0]], x1 = XT[u * 576 + xt_off[1]];
        float x2 = XT[u * 576 + xt_off[2]], x3 = XT[u * 576 + xt_off[3]];
        float ca0 = CM[u * 16 + cm_off[0]],       ca1 = CM[u * 16 + cm_off[1]];
        float ca2 = CM[u * 16 + cm_off[2]],       ca3 = CM[u * 16 + cm_off[3]];
        float cb0 = CM[256 + u * 16 + cm_off[0]], cb1 = CM[256 + u * 16 + cm_off[1]];
        float cb2 = CM[256 + u * 16 + cm_off[2]], cb3 = CM[256 + u * 16 + cm_off[3]];
        acc0.x += wa.x * x0 * ca0;  acc1.x += wb.x * x0 * cb0;
        acc0.y += wa.y * x1 * ca1;  acc1.y += wb.y * x1 * cb1;
        acc0.z += wa.z * x2 * ca2;  acc1.z += wb.z * x2 * cb2;
        acc0.w += wa.w * x3 * ca3;  acc1.w += wb.w * x3 * cb3;
    }

    // cross-thread c-reduction: threads {q, q+9, q+18, q+27} hold c=0..3 partials
    // for the same four (o,k) pairs (element-wise), per v. RED aliases XR (dead).
    float4* RED = (float4*)POOL;
    RED[sl * 36 + q]       = make_float4(acc0.x, acc0.y, acc0.z, acc0.w);
    RED[576 + sl * 36 + q] = make_float4(acc1.x, acc1.y, acc1.z, acc1.w);
    __syncthreads();
    if (q < 9) {
#pragma unroll
        for (int vi = 0; vi < 2; ++vi) {
            float4 t0 = RED[vi * 576 + sl * 36 + q];
            float4 t1 = RED[vi * 576 + sl * 36 + q + 9];
            float4 t2 = RED[vi * 576 + sl * 36 + q + 18];
            float4 t3 = RED[vi * 576 + sl * 36 + q + 27];
            float tot[4] = { t0.x + t1.x + t2.x + t3.x,
                             t0.y + t1.y + t2.y + t3.y,
                             t0.z + t1.z + t2.z + t3.z,
                             t0.w + t1.w + t2.w + t3.w };
            float* mp = mapped + (v0 + vi) * (SS * 36) + s * 36;
#pragma unroll
            for (int e = 0; e < 4; ++e) {
                int r = 4 * q + e;        // r = o*9 + k  (c=0 block)
                int o = r / 9, k = r % 9;
                mp[k * 4 + o] = tot[e];
            }
        }
    }
}

// Fold with torch's channel reinterpretation: flat channel (k*4+o) read back as (c*9+i*3+j)
__global__ void fold_kernel(const float* __restrict__ mapped, float* __restrict__ out) {
    int t = blockIdx.x * blockDim.x + threadIdx.x;
    if (t >= NB * CC * HH * WW) return;
    int xx = t & 31, y = (t >> 5) & 31, c = (t >> 10) & 3, v = t >> 12;
    float sum = 0.f;
#pragma unroll
    for (int i = 0; i < 3; ++i) {
        int h = y + 1 - i;
        if (h < 0 || h >= HH) continue;
#pragma unroll
        for (int j = 0; j < 3; ++j) {
            int w = xx + 1 - j;
            if (w < 0 || w >= WW) continue;
            sum += mapped[v * (SS * 36) + (h * 32 + w) * 36 + (c * 9 + i * 3 + j)];
        }
    }
    out[t] = sum;
}

extern "C" void kernel_launch(void* const* d_in, const int* in_sizes, int n_in,
                              void* d_out, int out_size, void* d_ws, size_t ws_size,
                              hipStream_t stream) {
    const float* x    = (const float*)d_in[0];
    const float* wgt  = (const float*)d_in[1];
    const float* cmap = (const float*)d_in[2];
    const float* mask = (const float*)d_in[3];
    float* out = (float*)d_out;

    float* mapped = (float*)d_ws;                 // 589,824 floats = 2.36 MB

    main_kernel<<<dim3(SS / 16, NB / 2), 576, 0, stream>>>(x, wgt, cmap, mask, mapped);
    fold_kernel<<<(NB * CC * HH * WW + 255) / 256, 256, 0, stream>>>(mapped, out);
}